// Round 3
// baseline (136.275 us; speedup 1.0000x reference)
//
#include <hip/hip_runtime.h>

#define NS     1500
#define NT     1500
#define NRR    4
#define DD     64
#define NBB    200
#define RJ     25                   // j's per wave (60 j-waves = 1500 exactly)
#define JTILES 15                   // j-tiles of 100 (4 waves x 25)
#define ITILES 17
#define TI     89                   // i rows staged in LDS (17*89 = 1513 >= 1500)
#define NCOMP  (NRR * ITILES * JTILES)   // 1020 compute blocks
#define NANCH  36                   // anchor blocks
#define NBLK   (NCOMP + NANCH)      // 1056 total = ~4.1 blocks/CU
#define EPS    3.0

// ws layout: [0..3] loss_all, [4..7] loss_alm, [8] counter (uint), 64B memset
__global__ __launch_bounds__(256) void fused_loss_kernel(
    const float* __restrict__ emb_s,
    const float* __restrict__ emb_t,
    const int*  __restrict__ rows,
    const int*  __restrict__ cols,
    float* __restrict__ ws,
    float* __restrict__ out)
{
    __shared__ float s_tile[TI * DD];
    __shared__ float red[4];

    const int tid  = threadIdx.x;
    const int wave = tid >> 6;
    const int lane = tid & 63;
    const int b    = blockIdx.x;

    if (b >= NCOMP) {
        // ---------------- anchor path: 36 blocks cover 200 pairs ----------
        const int ab = b - NCOMP;
        const int k = wave, d = lane;
        float acc = 0.f;
        for (int p = ab; p < NBB; p += NANCH) {
            const int r = rows[p];
            const int c = cols[p];
            acc += fabsf(emb_s[(r * NRR + k) * DD + d]
                       - emb_t[(c * NRR + k) * DD + d]);
        }
        #pragma unroll
        for (int off = 32; off > 0; off >>= 1)
            acc += __shfl_down(acc, off, 64);
        if (lane == 0) atomicAdd(&ws[4 + k], acc);
    } else {
        // ---------------- all-pairs path ----------------------------------
        const int k  = b / (ITILES * JTILES);
        const int rr = b % (ITILES * JTILES);
        const int it = rr / JTILES;
        const int jt = rr % JTILES;
        const int i0 = it * TI;
        const int ni = (NS - i0 < TI) ? (NS - i0) : TI;
        const int j0 = jt * (RJ * 4) + wave * RJ;

        // stage s tile [ni][64] via float4
        const float4* s4g = (const float4*)emb_s;
        float4* st4 = (float4*)s_tile;
        for (int u = tid; u < ni * 16; u += 256) {
            const int i = u >> 4, c = u & 15;
            st4[u] = s4g[((i0 + i) * NRR + k) * 16 + c];
        }

        // 25 t-columns in registers: tj[r] = t[j0+r][k][lane]
        float tj[RJ];
        #pragma unroll
        for (int r = 0; r < RJ; ++r)
            tj[r] = emb_t[((j0 + r) * NRR + k) * DD + lane];

        __syncthreads();

        float acc[8];
        #pragma unroll
        for (int a = 0; a < 8; ++a) acc[a] = 0.f;

        #pragma unroll 4
        for (int ii = 0; ii < ni; ++ii) {
            const float sv = s_tile[ii * DD + lane];
            #pragma unroll
            for (int r = 0; r < RJ; ++r)
                acc[r & 7] += fabsf(sv - tj[r]);
        }

        float a = ((acc[0] + acc[1]) + (acc[2] + acc[3]))
                + ((acc[4] + acc[5]) + (acc[6] + acc[7]));

        #pragma unroll
        for (int off = 32; off > 0; off >>= 1)
            a += __shfl_down(a, off, 64);
        if (lane == 0) red[wave] = a;
        __syncthreads();
        if (tid == 0)
            atomicAdd(&ws[k], (red[0] + red[1]) + (red[2] + red[3]));
    }

    // ---------------- last-block finalize ---------------------------------
    __threadfence();
    if (tid == 0) {
        unsigned old = atomicAdd((unsigned*)&ws[8], 1u);
        if (old == (unsigned)(NBLK - 1)) {
            __threadfence();
            double la[4], lm[4];
            #pragma unroll
            for (int k = 0; k < 4; ++k) {
                la[k] = (double)atomicAdd(&ws[k], 0.f);      // coherent read
                lm[k] = (double)atomicAdd(&ws[4 + k], 0.f);
            }
            const double nbB   = (double)NBB;
            const double nbNot = (double)NS * (double)NT - nbB;
            const double params[4] = {0.4, 0.2, 0.2, 0.2};
            double ret = 0.0;
            for (int k = 0; k < 4; ++k) {
                const double notalm = la[k] - lm[k];
                const double lk = lm[k] * nbNot + (EPS * nbNot - notalm) * nbB;
                ret += params[k] * lk;
            }
            ret = ret / (double)DD / ((double)NS * (double)NT);
            out[0] = (float)ret;
        }
    }
}

extern "C" void kernel_launch(void* const* d_in, const int* in_sizes, int n_in,
                              void* d_out, int out_size, void* d_ws, size_t ws_size,
                              hipStream_t stream)
{
    const float* emb_s = (const float*)d_in[0];
    const float* emb_t = (const float*)d_in[1];
    const int*   rows  = (const int*)d_in[2];
    const int*   cols  = (const int*)d_in[3];
    float* out = (float*)d_out;
    float* ws  = (float*)d_ws;

    hipMemsetAsync(ws, 0, 64, stream);
    fused_loss_kernel<<<NBLK, 256, 0, stream>>>(emb_s, emb_t, rows, cols, ws, out);
}